// Round 8
// baseline (237.753 us; speedup 1.0000x reference)
//
#include <hip/hip_runtime.h>
#include <hip/hip_bf16.h>

typedef __attribute__((ext_vector_type(8))) short s16x8;
typedef __attribute__((ext_vector_type(4))) float f32x4;
typedef __attribute__((ext_vector_type(4))) unsigned int u32x4;

#define BATCH 8
#define NPIX  4096
#define CCH   256
#define RCH   32
#define KVT   64
#define NT    (NPIX / KVT)
#define THR   8.0f

__device__ __forceinline__ unsigned short f2bf(float f) {
  __hip_bfloat16 h = __float2bfloat16(f);
  return __builtin_bit_cast(unsigned short, h);
}

__device__ __forceinline__ unsigned int pack_bf16(float lo, float hi) {
  return (unsigned int)f2bf(lo) | ((unsigned int)f2bf(hi) << 16);
}

// load 8 consecutive fp32 and convert to bf16x8 fragment
__device__ __forceinline__ s16x8 ld_bf8(const float* p) {
  float4 f0 = *reinterpret_cast<const float4*>(p);
  float4 f1 = *reinterpret_cast<const float4*>(p + 4);
  s16x8 r;
  r[0] = (short)f2bf(f0.x); r[1] = (short)f2bf(f0.y);
  r[2] = (short)f2bf(f0.z); r[3] = (short)f2bf(f0.w);
  r[4] = (short)f2bf(f1.x); r[5] = (short)f2bf(f1.y);
  r[6] = (short)f2bf(f1.z); r[7] = (short)f2bf(f1.w);
  return r;
}

// ---------------------------------------------------------------------------
// Kernel 0 (tiny): build wqk^T (64x256) and wv^T (256x256) in bf16.
// ---------------------------------------------------------------------------
__global__ void wprep_kernel(const float* __restrict__ wq,
                             const float* __restrict__ wk,
                             const float* __restrict__ wv,
                             unsigned short* __restrict__ wqkT,
                             unsigned short* __restrict__ wvT) {
  int stride = gridDim.x * blockDim.x;
  int i0 = blockIdx.x * blockDim.x + threadIdx.x;
  for (int i = i0; i < 64 * CCH; i += stride) {
    int d = i >> 8, c = i & 255;
    float v = (d < RCH) ? wq[c * RCH + d] : wk[c * RCH + (d - RCH)];
    wqkT[i] = f2bf(v);
  }
  for (int i = i0; i < CCH * CCH; i += stride) {
    int d = i >> 8, c = i & 255;
    wvT[i] = f2bf(wv[c * CCH + d]);
  }
}

// ---------------------------------------------------------------------------
// Kernel 1: q,k projection with relu; reads x fp32 directly (cast fused).
// ---------------------------------------------------------------------------
__global__ void qk_proj_kernel(const float* __restrict__ x,
                               const unsigned short* __restrict__ wqkT,
                               const float* __restrict__ bq,
                               const float* __restrict__ bk,
                               unsigned short* __restrict__ qb,
                               unsigned short* __restrict__ kb) {
  int t = threadIdx.x;
  int w = t >> 6, l = t & 63, g = l >> 4, lc = l & 15;
  int row0 = blockIdx.x * 64 + w * 16;
  f32x4 zero = {0.f, 0.f, 0.f, 0.f};
  f32x4 acc[4];
  for (int ct = 0; ct < 4; ++ct) acc[ct] = zero;
  for (int ks = 0; ks < 8; ++ks) {
    s16x8 a = ld_bf8(x + (size_t)(row0 + lc) * CCH + ks * 32 + g * 8);
    for (int ct = 0; ct < 4; ++ct) {
      s16x8 bfr = *reinterpret_cast<const s16x8*>(
          wqkT + (size_t)(ct * 16 + lc) * CCH + ks * 32 + g * 8);
      acc[ct] = __builtin_amdgcn_mfma_f32_16x16x32_bf16(a, bfr, acc[ct], 0, 0, 0);
    }
  }
  for (int ct = 0; ct < 4; ++ct) {
    int col = ct * 16 + lc;
    float bias = (col < RCH) ? bq[col] : bk[col - RCH];
    for (int r = 0; r < 4; ++r) {
      int row = row0 + 4 * g + r;
      float v = fmaxf(acc[ct][r] + bias, 0.f);
      if (col < RCH) qb[(size_t)row * RCH + col] = f2bf(v);
      else           kb[(size_t)row * RCH + (col - RCH)] = f2bf(v);
    }
  }
}

// ---------------------------------------------------------------------------
// Kernel 2: v projection, stored transposed vT[b][d][n]; x fp32 direct.
// ---------------------------------------------------------------------------
__global__ void v_proj_kernel(const float* __restrict__ x,
                              const unsigned short* __restrict__ wvT,
                              const float* __restrict__ bv,
                              unsigned short* __restrict__ vT) {
  int t = threadIdx.x;
  int w = t >> 6, l = t & 63, g = l >> 4, lc = l & 15;
  int idx = blockIdx.x;
  int b = idx & 7; idx >>= 3;
  int dt = idx & 3; int nt = idx >> 2;
  int d0 = dt * 64 + w * 16;
  int n0 = nt * 64;
  f32x4 zero = {0.f, 0.f, 0.f, 0.f};
  f32x4 acc[4];
  for (int ct = 0; ct < 4; ++ct) acc[ct] = zero;
  for (int ks = 0; ks < 8; ++ks) {
    s16x8 a = *reinterpret_cast<const s16x8*>(
        wvT + (size_t)(d0 + lc) * CCH + ks * 32 + g * 8);
    for (int ct = 0; ct < 4; ++ct) {
      s16x8 bfr = ld_bf8(
          x + ((size_t)b * NPIX + n0 + ct * 16 + lc) * CCH + ks * 32 + g * 8);
      acc[ct] = __builtin_amdgcn_mfma_f32_16x16x32_bf16(a, bfr, acc[ct], 0, 0, 0);
    }
  }
  for (int ct = 0; ct < 4; ++ct) {
    for (int r = 0; r < 4; ++r) {
      int d = d0 + 4 * g + r;
      int n = n0 + ct * 16 + lc;
      vT[((size_t)b * CCH + d) * NPIX + n] = f2bf(acc[ct][r] + bv[d]);
    }
  }
}

// ---------------------------------------------------------------------------
// Kernel 3: flash attention + residual. Symmetric waves, in-register P,
// P broadcast via small LDS, V direct from L2, channel-split PV.
// Block = 1 batch x 64 queries, 4 waves (256 thr), grid 512.
//   Each wave: QK for its 16 q (K rows pre-permuted so S^T lands in PV
//   A-frag order), softmax in-register, P -> 2 swizzled b128 LDS writes.
//   After ONE barrier: every wave PVs ALL 64 q for its 64-ch slice,
//   reading P A-frags (8 b128, conflict-free) and V from global (L2).
// Defer-max THR=8 (wave-global m); per-lane partial lsum reduced at end.
// ---------------------------------------------------------------------------
__global__ __launch_bounds__(256, 2)
void attn_kernel(const unsigned short* __restrict__ qb,
                 const unsigned short* __restrict__ kb,
                 const unsigned short* __restrict__ vT,
                 const float* __restrict__ x,
                 float* __restrict__ out) {
  // P[p][qg][q=lc][h][g][8 bf16], 128B per q-row, XOR-swizzled
  __shared__ __attribute__((aligned(16))) unsigned short Plds[2][4 * 16 * 64];
  __shared__ float scLds[2][4];
  __shared__ int   flLds[2][4];
  __shared__ float lsumLds[64];

  int b  = blockIdx.x & 7;         // batch == XCD -> vT/K/Q L2-resident
  int qt = blockIdx.x >> 3;        // 0..63
  int t  = threadIdx.x;
  int w = t >> 6, l = t & 63, g = l >> 4, lc = l & 15;
  const size_t bN = (size_t)b * NPIX;
  f32x4 zero = {0.f, 0.f, 0.f, 0.f};

  const unsigned short* kbase = kb + bN * RCH;
  const unsigned short* vbase = vT + (size_t)b * CCH * NPIX;

  // Q fragment (B-operand of QK): q = qt*64 + w*16 + lc
  int qrow = qt * 64 + w * 16 + lc;
  s16x8 qfrag = *reinterpret_cast<const s16x8*>(qb + (bN + qrow) * RCH + g * 8);

  // K pre-permuted rows: kf[ct] -> S keys cto[ct] + 8g + r
  int krb = 8 * (lc >> 2) + (lc & 3);
  const int cto[4] = {0, 4, 32, 36};

  // V rows for this wave's channel slice: ch = 64w + cc*16 + lc
  const unsigned short* vrow[4];
  #pragma unroll
  for (int cc = 0; cc < 4; ++cc)
    vrow[cc] = vbase + (size_t)(64 * w + cc * 16 + lc) * NPIX;

  unsigned int swz = (lc & 7) << 4;

  f32x4 o[4][4];                   // [qg][cc]
  #pragma unroll
  for (int qg = 0; qg < 4; ++qg)
    #pragma unroll
    for (int cc = 0; cc < 4; ++cc) o[qg][cc] = zero;
  float m = -1e30f, lsum = 0.f;

  // prologue: K tile 0
  s16x8 kf[4];
  #pragma unroll
  for (int ct = 0; ct < 4; ++ct)
    kf[ct] = *reinterpret_cast<const s16x8*>(
        kbase + (size_t)(cto[ct] + krb) * RCH + g * 8);

  for (int tix = 0; tix < NT; ++tix) {
    int p = tix & 1;
    int kv0 = tix * KVT;
    bool nx = (tix + 1) < NT;

    // ---- V loads for THIS tile, issued first (L2 latency hides under QK) --
    s16x8 vb[4][2];
    #pragma unroll
    for (int cc = 0; cc < 4; ++cc)
      #pragma unroll
      for (int h = 0; h < 2; ++h)
        vb[cc][h] = *reinterpret_cast<const s16x8*>(
            vrow[cc] + kv0 + 32 * h + 8 * g);

    // ---- QK^T: S^T in PV-ready key order ----
    f32x4 s[4];
    #pragma unroll
    for (int ct = 0; ct < 4; ++ct)
      s[ct] = __builtin_amdgcn_mfma_f32_16x16x32_bf16(kf[ct], qfrag, zero, 0, 0, 0);

    // prefetch next K tile
    if (nx) {
      #pragma unroll
      for (int ct = 0; ct < 4; ++ct)
        kf[ct] = *reinterpret_cast<const s16x8*>(
            kbase + (size_t)(kv0 + KVT + cto[ct] + krb) * RCH + g * 8);
    }

    // ---- softmax (wave-global max, deferred) ----
    float pmax = s[0][0];
    #pragma unroll
    for (int ct = 0; ct < 4; ++ct)
      #pragma unroll
      for (int r = 0; r < 4; ++r) pmax = fmaxf(pmax, s[ct][r]);

    float sc = 1.f;
    int resc = !__all(pmax - m <= THR);
    if (resc) {
      #pragma unroll
      for (int off = 1; off <= 32; off <<= 1)
        pmax = fmaxf(pmax, __shfl_xor(pmax, off));
      float mnew = fmaxf(m, pmax);
      sc = __expf(m - mnew);
      m = mnew;
    }

    float psum = 0.f;
    unsigned int pk[4][2];
    #pragma unroll
    for (int ct = 0; ct < 4; ++ct) {
      float p0 = __expf(s[ct][0] - m);
      float p1 = __expf(s[ct][1] - m);
      float p2 = __expf(s[ct][2] - m);
      float p3 = __expf(s[ct][3] - m);
      psum += (p0 + p1) + (p2 + p3);
      pk[ct][0] = pack_bf16(p0, p1);
      pk[ct][1] = pack_bf16(p2, p3);
    }
    lsum = lsum * sc + psum;

    // ---- P broadcast: 2 swizzled b128 writes ----
    {
      char* pbase = (char*)&Plds[p][0] + w * 2048 + lc * 128;
      u32x4 W0 = {pk[0][0], pk[0][1], pk[1][0], pk[1][1]};
      u32x4 W1 = {pk[2][0], pk[2][1], pk[3][0], pk[3][1]};
      *reinterpret_cast<u32x4*>(pbase + ((g * 16) ^ swz)) = W0;
      *reinterpret_cast<u32x4*>(pbase + ((64 + g * 16) ^ swz)) = W1;
    }
    if (l == 0) { scLds[p][w] = sc; flLds[p][w] = resc; }

    __syncthreads();

    // ---- rescale O per q-group (uniform scalars) ----
    int4 fl = *reinterpret_cast<const int4*>(&flLds[p][0]);
    if (fl.x | fl.y | fl.z | fl.w) {
      #pragma unroll
      for (int qg = 0; qg < 4; ++qg) {
        float sq = scLds[p][qg];
        #pragma unroll
        for (int cc = 0; cc < 4; ++cc)
          #pragma unroll
          for (int r = 0; r < 4; ++r) o[qg][cc][r] *= sq;
      }
    }

    // ---- PV: A = P from LDS (all 4 q-groups), B = V regs ----
    #pragma unroll
    for (int qg = 0; qg < 4; ++qg) {
      const char* pb = (const char*)&Plds[p][0] + qg * 2048 + lc * 128;
      s16x8 pa0 = *reinterpret_cast<const s16x8*>(pb + ((g * 16) ^ swz));
      s16x8 pa1 = *reinterpret_cast<const s16x8*>(pb + ((64 + g * 16) ^ swz));
      #pragma unroll
      for (int cc = 0; cc < 4; ++cc) {
        o[qg][cc] = __builtin_amdgcn_mfma_f32_16x16x32_bf16(
            pa0, vb[cc][0], o[qg][cc], 0, 0, 0);
        o[qg][cc] = __builtin_amdgcn_mfma_f32_16x16x32_bf16(
            pa1, vb[cc][1], o[qg][cc], 0, 0, 0);
      }
    }
    // no second barrier: next tile writes the other P buffer
  }

  // ---- lsum: reduce g-copies, share across waves ----
  lsum += __shfl_xor(lsum, 16);
  lsum += __shfl_xor(lsum, 32);
  if (l < 16) lsumLds[w * 16 + l] = lsum;
  __syncthreads();

  #pragma unroll
  for (int qg = 0; qg < 4; ++qg) {
    f32x4 l4 = *reinterpret_cast<const f32x4*>(&lsumLds[qg * 16 + 4 * g]);
    f32x4 rl;
    #pragma unroll
    for (int r = 0; r < 4; ++r) rl[r] = 1.0f / l4[r];
    #pragma unroll
    for (int cc = 0; cc < 4; ++cc) {
      #pragma unroll
      for (int r = 0; r < 4; ++r) {
        size_t row = bN + qt * 64 + qg * 16 + 4 * g + r;
        size_t idx = row * CCH + 64 * w + cc * 16 + lc;
        out[idx] = o[qg][cc][r] * rl[r] + x[idx];
      }
    }
  }
}

// ---------------------------------------------------------------------------
extern "C" void kernel_launch(void* const* d_in, const int* in_sizes, int n_in,
                              void* d_out, int out_size, void* d_ws, size_t ws_size,
                              hipStream_t stream) {
  const float* x  = (const float*)d_in[0];
  const float* wq = (const float*)d_in[1];
  const float* bq = (const float*)d_in[2];
  const float* wk = (const float*)d_in[3];
  const float* bk = (const float*)d_in[4];
  const float* wv = (const float*)d_in[5];
  const float* bv = (const float*)d_in[6];
  float* out = (float*)d_out;

  unsigned short* ws   = (unsigned short*)d_ws;
  unsigned short* qb   = ws;                   // 8*4096*32  = 1,048,576
  unsigned short* kb   = qb + 1048576;         // 1,048,576
  unsigned short* vT   = kb + 1048576;         // 8*256*4096 = 8,388,608
  unsigned short* wqkT = vT + 8388608;         // 64*256 = 16,384
  unsigned short* wvT  = wqkT + 16384;         // 256*256 = 65,536

  wprep_kernel<<<dim3(320), dim3(256), 0, stream>>>(wq, wk, wv, wqkT, wvT);
  qk_proj_kernel<<<dim3(512), dim3(256), 0, stream>>>(x, wqkT, bq, bk, qb, kb);
  v_proj_kernel<<<dim3(2048), dim3(256), 0, stream>>>(x, wvT, bv, vT);
  attn_kernel<<<dim3(512), dim3(256), 0, stream>>>(qb, kb, vT, x, out);
}

// Round 9
// 166.721 us; speedup vs baseline: 1.4261x; 1.4261x over previous
//
#include <hip/hip_runtime.h>
#include <hip/hip_bf16.h>

typedef __attribute__((ext_vector_type(8))) short s16x8;
typedef __attribute__((ext_vector_type(4))) float f32x4;
typedef __attribute__((ext_vector_type(4))) unsigned int u32x4;

#define BATCH 8
#define NPIX  4096
#define CCH   256
#define RCH   32
#define KVT   64
#define NT    (NPIX / KVT)
#define THR   8.0f
#define LOG2E 1.4426950408889634f

__device__ __forceinline__ unsigned short f2bf(float f) {
  __hip_bfloat16 h = __float2bfloat16(f);
  return __builtin_bit_cast(unsigned short, h);
}

__device__ __forceinline__ unsigned int pack_bf16(float lo, float hi) {
  return (unsigned int)f2bf(lo) | ((unsigned int)f2bf(hi) << 16);
}

__device__ __forceinline__ void gload_lds16(const void* g, void* l) {
  __builtin_amdgcn_global_load_lds(
      (const __attribute__((address_space(1))) void*)g,
      (__attribute__((address_space(3))) void*)l, 16, 0, 0);
}

// ---------------------------------------------------------------------------
// Kernel 0: cast x -> bf16; build wqk^T (64x256) and wv^T (256x256) in bf16.
// ---------------------------------------------------------------------------
__global__ void prep_kernel(const float* __restrict__ x,
                            const float* __restrict__ wq,
                            const float* __restrict__ wk,
                            const float* __restrict__ wv,
                            unsigned short* __restrict__ xb,
                            unsigned short* __restrict__ wqkT,
                            unsigned short* __restrict__ wvT) {
  int stride = gridDim.x * blockDim.x;
  int i0 = blockIdx.x * blockDim.x + threadIdx.x;
  const int nx4 = BATCH * NPIX * CCH / 4;
  for (int i = i0; i < nx4; i += stride) {
    float4 v = reinterpret_cast<const float4*>(x)[i];
    ushort4 o;
    o.x = f2bf(v.x); o.y = f2bf(v.y); o.z = f2bf(v.z); o.w = f2bf(v.w);
    reinterpret_cast<ushort4*>(xb)[i] = o;
  }
  for (int i = i0; i < 64 * CCH; i += stride) {
    int d = i >> 8, c = i & 255;
    float v = (d < RCH) ? wq[c * RCH + d] : wk[c * RCH + (d - RCH)];
    wqkT[i] = f2bf(v);
  }
  for (int i = i0; i < CCH * CCH; i += stride) {
    int d = i >> 8, c = i & 255;
    wvT[i] = f2bf(wv[c * CCH + d]);
  }
}

// ---------------------------------------------------------------------------
// Kernel 1: q,k projection with relu; q additionally scaled by log2(e) so
// attention softmax can use exp2. rows flat over B*N; 64 cols = 32q+32k.
// ---------------------------------------------------------------------------
__global__ void qk_proj_kernel(const unsigned short* __restrict__ xb,
                               const unsigned short* __restrict__ wqkT,
                               const float* __restrict__ bq,
                               const float* __restrict__ bk,
                               unsigned short* __restrict__ qb,
                               unsigned short* __restrict__ kb) {
  int t = threadIdx.x;
  int w = t >> 6, l = t & 63, g = l >> 4, lc = l & 15;
  int row0 = blockIdx.x * 64 + w * 16;
  f32x4 zero = {0.f, 0.f, 0.f, 0.f};
  f32x4 acc[4];
  for (int ct = 0; ct < 4; ++ct) acc[ct] = zero;
  for (int ks = 0; ks < 8; ++ks) {
    s16x8 a = *reinterpret_cast<const s16x8*>(
        xb + (size_t)(row0 + lc) * CCH + ks * 32 + g * 8);
    for (int ct = 0; ct < 4; ++ct) {
      s16x8 bfr = *reinterpret_cast<const s16x8*>(
          wqkT + (size_t)(ct * 16 + lc) * CCH + ks * 32 + g * 8);
      acc[ct] = __builtin_amdgcn_mfma_f32_16x16x32_bf16(a, bfr, acc[ct], 0, 0, 0);
    }
  }
  for (int ct = 0; ct < 4; ++ct) {
    int col = ct * 16 + lc;
    float bias = (col < RCH) ? bq[col] : bk[col - RCH];
    for (int r = 0; r < 4; ++r) {
      int row = row0 + 4 * g + r;
      float v = fmaxf(acc[ct][r] + bias, 0.f);
      if (col < RCH) qb[(size_t)row * RCH + col] = f2bf(v * LOG2E);
      else           kb[(size_t)row * RCH + (col - RCH)] = f2bf(v);
    }
  }
}

// ---------------------------------------------------------------------------
// Kernel 2: v projection, stored transposed: vT[b][d][n]
// ---------------------------------------------------------------------------
__global__ void v_proj_kernel(const unsigned short* __restrict__ xb,
                              const unsigned short* __restrict__ wvT,
                              const float* __restrict__ bv,
                              unsigned short* __restrict__ vT) {
  int t = threadIdx.x;
  int w = t >> 6, l = t & 63, g = l >> 4, lc = l & 15;
  int idx = blockIdx.x;
  int b = idx & 7; idx >>= 3;
  int dt = idx & 3; int nt = idx >> 2;
  int d0 = dt * 64 + w * 16;
  int n0 = nt * 64;
  f32x4 zero = {0.f, 0.f, 0.f, 0.f};
  f32x4 acc[4];
  for (int ct = 0; ct < 4; ++ct) acc[ct] = zero;
  for (int ks = 0; ks < 8; ++ks) {
    s16x8 a = *reinterpret_cast<const s16x8*>(
        wvT + (size_t)(d0 + lc) * CCH + ks * 32 + g * 8);
    for (int ct = 0; ct < 4; ++ct) {
      s16x8 bfr = *reinterpret_cast<const s16x8*>(
          xb + ((size_t)b * NPIX + n0 + ct * 16 + lc) * CCH + ks * 32 + g * 8);
      acc[ct] = __builtin_amdgcn_mfma_f32_16x16x32_bf16(a, bfr, acc[ct], 0, 0, 0);
    }
  }
  for (int ct = 0; ct < 4; ++ct) {
    for (int r = 0; r < 4; ++r) {
      int d = d0 + 4 * g + r;
      int n = n0 + ct * 16 + lc;
      vT[((size_t)b * CCH + d) * NPIX + n] = f2bf(acc[ct][r] + bv[d]);
    }
  }
}

// ---------------------------------------------------------------------------
// Kernel 3: flash attention + residual. SYMMETRIC waves, P in-register.
// Block = 1 batch x 64 queries, 4 waves (256 thr), grid 512.
//   - K rows pre-permuted so swapped-QK output lands in PV A-frag order.
//   - V tile staged via global_load_lds (DMA, linear LDS dest); the XOR
//     swizzle is applied to the GLOBAL source granule index instead
//     (gr^(chb&7)), so reads stay conflict-free and writes cost no
//     wave instruction slots. Double-buffered, ONE barrier per tile.
//   - softmax in exp2 domain (q pre-scaled by log2e); defer-max THR=8;
//     wave-global m -> uniform rescale; partial lsum reduced at end.
// ---------------------------------------------------------------------------
__global__ __launch_bounds__(256, 2)
void attn_kernel(const unsigned short* __restrict__ qb,
                 const unsigned short* __restrict__ kb,
                 const unsigned short* __restrict__ vT,
                 const float* __restrict__ x,
                 float* __restrict__ out) {
  __shared__ __attribute__((aligned(16))) unsigned short Vlds[2][CCH * KVT];
  __shared__ float lsumLds[64];

  int b  = blockIdx.x & 7;         // batch == XCD -> vT/K/Q L2-resident
  int qt = blockIdx.x >> 3;        // 0..63
  int t  = threadIdx.x;
  int w = t >> 6, l = t & 63, g = l >> 4, lc = l & 15;
  const size_t bN = (size_t)b * NPIX;
  f32x4 zero = {0.f, 0.f, 0.f, 0.f};

  const unsigned short* kbase = kb + bN * RCH;
  const unsigned short* vbase = vT + (size_t)b * CCH * NPIX;

  // Q fragment (B-operand of QK): q = qt*64 + w*16 + lc
  int qrow = qt * 64 + w * 16 + lc;
  s16x8 qfrag = *reinterpret_cast<const s16x8*>(qb + (bN + qrow) * RCH + g * 8);

  // staging: thread covers ch = (t>>3) + 32i; SOURCE granule pre-swizzled
  // so the linear LDS write (t*16 + i*4096) matches the swizzled read.
  int chb = t >> 3, gr = t & 7;
  const unsigned short* vsrc =
      vbase + (size_t)chb * NPIX + ((gr ^ (chb & 7)) * 8);

  // K pre-permuted rows: kf[ct] -> S keys cto[ct] + 8g + r
  int krb = 8 * (lc >> 2) + (lc & 3);
  const int cto[4] = {0, 4, 32, 36};

  // PV read offsets (swizzled)
  unsigned int swz = (lc & 7) << 4;
  int vr0 = (g * 16) ^ swz;
  int vr1 = (64 + g * 16) ^ swz;

  f32x4 o[16];
  #pragma unroll
  for (int cc = 0; cc < 16; ++cc) o[cc] = zero;
  float m = -1e30f, lsum = 0.f;

  // ---- prologue: DMA-stage tile 0, load K tile 0 ----
  #pragma unroll
  for (int i = 0; i < 8; ++i)
    gload_lds16(vsrc + (size_t)i * 32 * NPIX,
                (char*)&Vlds[0][0] + i * 4096 + t * 16);
  s16x8 kf[4];
  #pragma unroll
  for (int ct = 0; ct < 4; ++ct)
    kf[ct] = *reinterpret_cast<const s16x8*>(
        kbase + (size_t)(cto[ct] + krb) * RCH + g * 8);
  __syncthreads();

  for (int tix = 0; tix < NT; ++tix) {
    int p = tix & 1;
    int kv0 = tix * KVT;
    bool nx = (tix + 1) < NT;

    // ---- DMA-stage next V tile into the other buffer ----
    if (nx) {
      #pragma unroll
      for (int i = 0; i < 8; ++i)
        gload_lds16(vsrc + kv0 + KVT + (size_t)i * 32 * NPIX,
                    (char*)&Vlds[p ^ 1][0] + i * 4096 + t * 16);
    }

    // ---- QK^T: S^T in PV-ready key order (exp2 domain) ----
    f32x4 s[4];
    #pragma unroll
    for (int ct = 0; ct < 4; ++ct)
      s[ct] = __builtin_amdgcn_mfma_f32_16x16x32_bf16(kf[ct], qfrag, zero, 0, 0, 0);

    // prefetch next K tile
    if (nx) {
      #pragma unroll
      for (int ct = 0; ct < 4; ++ct)
        kf[ct] = *reinterpret_cast<const s16x8*>(
            kbase + (size_t)(kv0 + KVT + cto[ct] + krb) * RCH + g * 8);
    }

    // ---- softmax (wave-global max, deferred) ----
    float pmax = s[0][0];
    #pragma unroll
    for (int ct = 0; ct < 4; ++ct)
      #pragma unroll
      for (int r = 0; r < 4; ++r) pmax = fmaxf(pmax, s[ct][r]);

    float sc = 1.f;
    int resc = !__all(pmax - m <= THR);
    if (resc) {
      #pragma unroll
      for (int off = 1; off <= 32; off <<= 1)
        pmax = fmaxf(pmax, __shfl_xor(pmax, off));
      float mnew = fmaxf(m, pmax);
      sc = exp2f(m - mnew);
      m = mnew;
    }

    float psum = 0.f;
    unsigned int pk[4][2];
    #pragma unroll
    for (int ct = 0; ct < 4; ++ct) {
      float p0 = exp2f(s[ct][0] - m);
      float p1 = exp2f(s[ct][1] - m);
      float p2 = exp2f(s[ct][2] - m);
      float p3 = exp2f(s[ct][3] - m);
      psum += (p0 + p1) + (p2 + p3);
      pk[ct][0] = pack_bf16(p0, p1);
      pk[ct][1] = pack_bf16(p2, p3);
    }
    lsum = lsum * sc + psum;

    // uniform O rescale (rare after warmup)
    if (resc) {
      #pragma unroll
      for (int cc = 0; cc < 16; ++cc)
        #pragma unroll
        for (int r = 0; r < 4; ++r) o[cc][r] *= sc;
    }

    // ---- PV: A = in-register P, B = V from LDS ----
    u32x4 a0u = {pk[0][0], pk[0][1], pk[1][0], pk[1][1]};
    u32x4 a1u = {pk[2][0], pk[2][1], pk[3][0], pk[3][1]};
    s16x8 pa0 = __builtin_bit_cast(s16x8, a0u);
    s16x8 pa1 = __builtin_bit_cast(s16x8, a1u);
    const char* pb = (const char*)&Vlds[p][0] + lc * 128;
    __builtin_amdgcn_s_setprio(1);
    #pragma unroll
    for (int cc = 0; cc < 16; ++cc) {
      s16x8 vb0 = *reinterpret_cast<const s16x8*>(pb + cc * 2048 + vr0);
      s16x8 vb1 = *reinterpret_cast<const s16x8*>(pb + cc * 2048 + vr1);
      o[cc] = __builtin_amdgcn_mfma_f32_16x16x32_bf16(pa0, vb0, o[cc], 0, 0, 0);
      o[cc] = __builtin_amdgcn_mfma_f32_16x16x32_bf16(pa1, vb1, o[cc], 0, 0, 0);
    }
    __builtin_amdgcn_s_setprio(0);

    __syncthreads();
  }

  // ---- lsum: reduce the 4 g-copies, redistribute to output layout ----
  lsum += __shfl_xor(lsum, 16);
  lsum += __shfl_xor(lsum, 32);
  if (l < 16) lsumLds[w * 16 + l] = lsum;
  __syncthreads();

  f32x4 l4 = *reinterpret_cast<const f32x4*>(&lsumLds[w * 16 + 4 * g]);
  f32x4 rl;
  #pragma unroll
  for (int r = 0; r < 4; ++r) rl[r] = 1.0f / l4[r];

  #pragma unroll
  for (int cc = 0; cc < 16; ++cc) {
    #pragma unroll
    for (int r = 0; r < 4; ++r) {
      size_t row = bN + qt * 64 + w * 16 + 4 * g + r;
      size_t idx = row * CCH + cc * 16 + lc;
      out[idx] = o[cc][r] * rl[r] + x[idx];
    }
  }
}

// ---------------------------------------------------------------------------
extern "C" void kernel_launch(void* const* d_in, const int* in_sizes, int n_in,
                              void* d_out, int out_size, void* d_ws, size_t ws_size,
                              hipStream_t stream) {
  const float* x  = (const float*)d_in[0];
  const float* wq = (const float*)d_in[1];
  const float* bq = (const float*)d_in[2];
  const float* wk = (const float*)d_in[3];
  const float* bk = (const float*)d_in[4];
  const float* wv = (const float*)d_in[5];
  const float* bv = (const float*)d_in[6];
  float* out = (float*)d_out;

  unsigned short* ws   = (unsigned short*)d_ws;
  unsigned short* qb   = ws;                   // 8*4096*32  = 1,048,576
  unsigned short* kb   = qb + 1048576;         // 1,048,576
  unsigned short* vT   = kb + 1048576;         // 8*256*4096 = 8,388,608
  unsigned short* xb   = vT + 8388608;         // 8,388,608
  unsigned short* wqkT = xb + 8388608;         // 64*256 = 16,384
  unsigned short* wvT  = wqkT + 16384;         // 256*256 = 65,536

  prep_kernel<<<dim3(2048), dim3(256), 0, stream>>>(x, wq, wk, wv, xb, wqkT, wvT);
  qk_proj_kernel<<<dim3(512), dim3(256), 0, stream>>>(xb, wqkT, bq, bk, qb, kb);
  v_proj_kernel<<<dim3(2048), dim3(256), 0, stream>>>(xb, wvT, bv, vT);
  attn_kernel<<<dim3(512), dim3(256), 0, stream>>>(qb, kb, vT, x, out);
}